// Round 6
// baseline (433.819 us; speedup 1.0000x reference)
//
#include <hip/hip_runtime.h>

typedef unsigned short u16;
typedef short bf16x8 __attribute__((ext_vector_type(8)));
typedef float f32x4 __attribute__((ext_vector_type(4)));

#define MFMA_BF16(a, b, c) __builtin_amdgcn_mfma_f32_16x16x32_bf16((a), (b), (c), 0, 0, 0)
#define ATT_SCALE 0.08838834764831845f  // 1/sqrt(128)

__device__ __forceinline__ u16 f2bf(float f) {
  union { float f; unsigned int u; } cv;
  cv.f = f;
  unsigned int u = cv.u + 0x7fffu + ((cv.u >> 16) & 1u);
  return (u16)(u >> 16);
}

// ---------------- prep: LN(x), AdaLN(latents), W transposes — one dispatch ----------------
// blocks [0,4096): x-LN row      [4096,6144): latent-AdaLN row
// blocks [6144,10240): Wq tile   [10240,14336): Wo tile   [14336,22528): Wkv tile
__global__ __launch_bounds__(256) void prep_kernel(
    const float* __restrict__ x, const float* __restrict__ ln_w,
    const float* __restrict__ ln_b, const float* __restrict__ latents,
    const float* __restrict__ t_emb, const float* __restrict__ ssg,
    const float* __restrict__ Wq, const float* __restrict__ Wo,
    const float* __restrict__ Wkv,
    u16* __restrict__ xk_out, u16* __restrict__ lat_out,
    u16* __restrict__ WqT, u16* __restrict__ WoT, u16* __restrict__ WkvT)
{
  __shared__ float shmem[32 * 33];
  const int blk = blockIdx.x;
  const int tid = threadIdx.x;
  if (blk < 6144) {
    const bool is_x = blk < 4096;
    const int row = is_x ? blk : blk - 4096;
    const float* src = is_x ? (x + (size_t)row * 2048) : (latents + (size_t)row * 2048);
    const float4* xr = (const float4*)src;
    float4 v0 = xr[tid];
    float4 v1 = xr[tid + 256];
    float sum = v0.x + v0.y + v0.z + v0.w + v1.x + v1.y + v1.z + v1.w;
    float sq  = v0.x*v0.x + v0.y*v0.y + v0.z*v0.z + v0.w*v0.w
              + v1.x*v1.x + v1.y*v1.y + v1.z*v1.z + v1.w*v1.w;
    #pragma unroll
    for (int off = 32; off > 0; off >>= 1) {
      sum += __shfl_xor(sum, off);
      sq  += __shfl_xor(sq, off);
    }
    if ((tid & 63) == 0) { shmem[tid >> 6] = sum; shmem[(tid >> 6) + 4] = sq; }
    __syncthreads();
    sum = shmem[0] + shmem[1] + shmem[2] + shmem[3];
    sq  = shmem[4] + shmem[5] + shmem[6] + shmem[7];
    const float mean = sum * (1.0f / 2048.0f);
    const float var  = sq * (1.0f / 2048.0f) - mean * mean;
    const float rstd = rsqrtf(var + 1e-5f);
    if (is_x) {
      const float4* w4 = (const float4*)ln_w;
      const float4* b4 = (const float4*)ln_b;
      ushort4* orow = (ushort4*)(xk_out + (size_t)row * 2048);
      #pragma unroll
      for (int j = 0; j < 2; ++j) {
        const int idx = tid + j * 256;
        const float4 v = j ? v1 : v0;
        const float4 ww = w4[idx];
        const float4 bb = b4[idx];
        ushort4 o;
        o.x = f2bf((v.x - mean) * rstd * ww.x + bb.x);
        o.y = f2bf((v.y - mean) * rstd * ww.y + bb.y);
        o.z = f2bf((v.z - mean) * rstd * ww.z + bb.z);
        o.w = f2bf((v.w - mean) * rstd * ww.w + bb.w);
        orow[idx] = o;
      }
    } else {
      const int bidx = row >> 9;
      const float4* te = (const float4*)(t_emb + (size_t)bidx * 3 * 2048);
      const float4* sg = (const float4*)ssg;
      ushort4* orow = (ushort4*)(lat_out + (size_t)row * 2048);
      #pragma unroll
      for (int j = 0; j < 2; ++j) {
        const int idx = tid + j * 256;
        const float4 v = j ? v1 : v0;
        const float4 t0 = te[idx];        // shift row
        const float4 t1 = te[512 + idx];  // scale row
        const float4 s0 = sg[idx];
        const float4 s1 = sg[512 + idx];
        ushort4 o;
        o.x = f2bf(((v.x - mean) * rstd) * (1.0f + t1.x + s1.x) + (t0.x + s0.x));
        o.y = f2bf(((v.y - mean) * rstd) * (1.0f + t1.y + s1.y) + (t0.y + s0.y));
        o.z = f2bf(((v.z - mean) * rstd) * (1.0f + t1.z + s1.z) + (t0.z + s0.z));
        o.w = f2bf(((v.w - mean) * rstd) * (1.0f + t1.w + s1.w) + (t0.w + s0.w));
        orow[idx] = o;
      }
    }
  } else {
    int t = blk - 6144;
    const float* in;
    u16* outp;
    int C, cx, ry;
    if (t < 4096)      { in = Wq;  outp = WqT;  C = 2048; cx = t & 63;  ry = t >> 6; }
    else if (t < 8192) { t -= 4096; in = Wo;  outp = WoT;  C = 2048; cx = t & 63;  ry = t >> 6; }
    else               { t -= 8192; in = Wkv; outp = WkvT; C = 4096; cx = t & 127; ry = t >> 7; }
    float (*tile)[33] = (float(*)[33])shmem;
    const int R = 2048;
    const int c0 = cx * 32;
    const int r0 = ry * 32;
    const int tx = tid & 31;
    const int ty = tid >> 5;   // 0..7
    #pragma unroll
    for (int i = 0; i < 4; ++i)
      tile[ty + i * 8][tx] = in[(size_t)(r0 + ty + i * 8) * C + c0 + tx];
    __syncthreads();
    #pragma unroll
    for (int i = 0; i < 4; ++i)
      outp[(size_t)(c0 + ty + i * 8) * R + r0 + tx] = f2bf(tile[tx][ty + i * 8]);
  }
}

// ---------------- bf16 MFMA GEMM, explicit SW pipeline, BK=64 ----------------
// TMPL==3: fused q+kv dispatch (BM=128). blocks [0,256): q proj tiles;
//          [256,1280): kv proj tiles.
// TMPL==2: out proj (BM=64), fused bias + gate, fp32 out.
// epilogues: mode 0 q -> out_q bf16 (B,H,L,C) * ATT_SCALE
//            mode 1 kv -> out_k bf16 (B,H,K,C), out_vT bf16 (B,H,C,K)
//            mode 2 out -> out_f fp32 (B*L, D) * gate
template<int BM, int TMPL>
__global__ __launch_bounds__(256) void gemm_kernel(
    const u16* __restrict__ A0, const u16* __restrict__ BT0,
    const u16* __restrict__ A1, const u16* __restrict__ BT1,
    const float* __restrict__ bias0, const float* __restrict__ bias1,
    u16* __restrict__ out_q, u16* __restrict__ out_k, u16* __restrict__ out_vT,
    float* __restrict__ out_f,
    const float* __restrict__ t_emb, const float* __restrict__ ssg)
{
  constexpr int TI = BM / 32;
  constexpr int Kd = 2048;
  __shared__ u16 As[2][BM][40];      // padded: stride 40 elem = 80B
  __shared__ u16 Bs[2][128][40];
  const int tid  = threadIdx.x;
  const int lane = tid & 63;
  const int wv   = tid >> 6;
  const int wm   = wv & 1, wn = wv >> 1;
  const int quad = lane >> 4, lq = lane & 15;

  int mode, m0, n0;
  const u16 *A, *BT;
  const float* bias;
  if (TMPL == 3) {
    int t = blockIdx.x;
    if (t < 256) { mode = 0; A = A0; BT = BT0; bias = bias0;
                   m0 = (t >> 4) * 128; n0 = (t & 15) * 128; }
    else { t -= 256; mode = 1; A = A1; BT = BT1; bias = bias1;
           m0 = (t >> 5) * 128; n0 = (t & 31) * 128; }
  } else {
    mode = 2; A = A0; BT = BT0; bias = bias0;
    m0 = blockIdx.y * BM; n0 = blockIdx.x * 128;
  }

  f32x4 acc[TI][4];
  #pragma unroll
  for (int i = 0; i < TI; ++i)
    #pragma unroll
    for (int j = 0; j < 4; ++j)
      acc[i][j] = (f32x4){0.f, 0.f, 0.f, 0.f};

  const int rB  = tid >> 1;
  const int hfB = (tid & 1) * 16;
  const u16* gB = BT + (size_t)(n0 + rB) * Kd + hfB;
  const int rA  = (BM == 128) ? (tid >> 1) : (tid >> 2);
  const int hA  = (BM == 128) ? 0 : ((tid >> 1) & 1);
  const int hfA = (tid & 1) * 16;
  const u16* gA = A + (size_t)(m0 + rA) * Kd + hA * 32 + hfA;

  // explicit pipeline: preload tile 0; each iter stores, barriers, issues
  // next-tile loads BEFORE the MFMA block (wrapped idx on last iter).
  uint4 a00, a01, a10, a11, b00, b01, b10, b11;
  a00 = *(const uint4*)(gA);
  a01 = *(const uint4*)(gA + 8);
  if (BM == 128) {
    a10 = *(const uint4*)(gA + 32);
    a11 = *(const uint4*)(gA + 40);
  }
  b00 = *(const uint4*)(gB);
  b01 = *(const uint4*)(gB + 8);
  b10 = *(const uint4*)(gB + 32);
  b11 = *(const uint4*)(gB + 40);

  for (int k0 = 0; k0 < Kd; k0 += 64) {
    __syncthreads();                 // prior iteration's LDS reads done
    *(uint4*)&As[hA][rA][hfA]     = a00;
    *(uint4*)&As[hA][rA][hfA + 8] = a01;
    if (BM == 128) {
      *(uint4*)&As[1][rA][hfA]     = a10;
      *(uint4*)&As[1][rA][hfA + 8] = a11;
    }
    *(uint4*)&Bs[0][rB][hfB]     = b00;
    *(uint4*)&Bs[0][rB][hfB + 8] = b01;
    *(uint4*)&Bs[1][rB][hfB]     = b10;
    *(uint4*)&Bs[1][rB][hfB + 8] = b11;
    __syncthreads();

    const int kn = (k0 + 64 < Kd) ? k0 + 64 : 0;   // wrap: redundant last load
    a00 = *(const uint4*)(gA + kn);
    a01 = *(const uint4*)(gA + kn + 8);
    if (BM == 128) {
      a10 = *(const uint4*)(gA + kn + 32);
      a11 = *(const uint4*)(gA + kn + 40);
    }
    b00 = *(const uint4*)(gB + kn);
    b01 = *(const uint4*)(gB + kn + 8);
    b10 = *(const uint4*)(gB + kn + 32);
    b11 = *(const uint4*)(gB + kn + 40);

    #pragma unroll
    for (int kk = 0; kk < 2; ++kk) {
      bf16x8 av[TI], bv[4];
      #pragma unroll
      for (int i = 0; i < TI; ++i)
        av[i] = *(const bf16x8*)&As[kk][wm * (BM / 2) + i * 16 + lq][quad * 8];
      #pragma unroll
      for (int j = 0; j < 4; ++j)
        bv[j] = *(const bf16x8*)&Bs[kk][wn * 64 + j * 16 + lq][quad * 8];
      #pragma unroll
      for (int i = 0; i < TI; ++i)
        #pragma unroll
        for (int j = 0; j < 4; ++j)
          acc[i][j] = MFMA_BF16(av[i], bv[j], acc[i][j]);
    }
  }

  // epilogue; C/D layout: col = lane&15, row = quad*4 + reg
  #pragma unroll
  for (int i = 0; i < TI; ++i) {
    const int mlb = m0 + wm * (BM / 2) + i * 16 + quad * 4;
    #pragma unroll
    for (int j = 0; j < 4; ++j) {
      const int n = n0 + wn * 64 + j * 16 + lq;
      const float bs = bias[n];
      if (mode == 0) {
        const int h = n >> 7, c = n & 127;
        #pragma unroll
        for (int rr = 0; rr < 4; ++rr) {
          const int m = mlb + rr;
          const int bb = m >> 9, l = m & 511;
          out_q[((size_t)(bb * 16 + h) * 512 + l) * 128 + c] =
              f2bf((acc[i][j][rr] + bs) * ATT_SCALE);
        }
      } else if (mode == 1) {
        if (n < 2048) {
          const int h = n >> 7, c = n & 127;
          #pragma unroll
          for (int rr = 0; rr < 4; ++rr) {
            const int m = mlb + rr;
            const int bb = m >> 10, kk = m & 1023;
            out_k[((size_t)(bb * 16 + h) * 1024 + kk) * 128 + c] = f2bf(acc[i][j][rr] + bs);
          }
        } else {
          const int n2 = n - 2048;
          const int h = n2 >> 7, c = n2 & 127;
          #pragma unroll
          for (int rr = 0; rr < 4; ++rr) {
            const int m = mlb + rr;
            const int bb = m >> 10, kk = m & 1023;
            out_vT[((size_t)(bb * 16 + h) * 128 + c) * 1024 + kk] = f2bf(acc[i][j][rr] + bs);
          }
        }
      } else {
        #pragma unroll
        for (int rr = 0; rr < 4; ++rr) {
          const int m = mlb + rr;
          const int bb = m >> 9;
          const float g = t_emb[((size_t)bb * 3 + 2) * 2048 + n] + ssg[2 * 2048 + n];
          out_f[(size_t)m * 2048 + n] = (acc[i][j][rr] + bs) * g;
        }
      }
    }
  }
}

// ---------------- flash attention: LDS-staged K/V, pre-barrier staging ----------------
// per (b,h, 64-row q tile); Q pre-scaled by 1/sqrt(C) in q-proj epilogue.
__global__ __launch_bounds__(256) void attn_kernel(
    const u16* __restrict__ qb, const u16* __restrict__ kb,
    const u16* __restrict__ vT, const int* __restrict__ k_lens,
    const int* __restrict__ q_lens, u16* __restrict__ ao)
{
  __shared__ u16 Ks[64][132];   // keys x C; stride 264B -> 2-way banks (free)
  __shared__ u16 Vs[128][68];   // c x keys; stride 136B
  __shared__ u16 Ps[64][68];    // q x keys (wave-private 16-row bands)
  const int tid  = threadIdx.x;
  const int w    = tid >> 6;
  const int lane = tid & 63;
  const int quad = lane >> 4, lq = lane & 15;
  const int bh = blockIdx.y;           // b*16 + h
  const int b  = bh >> 4;
  const int l0 = blockIdx.x * 64;
  const int kl = k_lens[b];
  const int ql = q_lens[b];

  bf16x8 qf[4];
  {
    const u16* qp = qb + ((size_t)bh * 512 + l0 + w * 16 + lq) * 128 + quad * 8;
    #pragma unroll
    for (int ks = 0; ks < 4; ++ks)
      qf[ks] = *(const bf16x8*)(qp + ks * 32);
  }

  const int krow = tid >> 4;
  const int kcol = tid & 15;
  const u16* kg = kb + ((size_t)bh * 1024 + krow) * 128 + kcol * 8;
  const int vrow = tid >> 3;
  const int vcol = tid & 7;
  const u16* vg = vT + (size_t)bh * 128 * 1024 + (size_t)vrow * 1024 + vcol * 8;

  f32x4 o[8];
  #pragma unroll
  for (int j = 0; j < 8; ++j) o[j] = (f32x4){0.f, 0.f, 0.f, 0.f};
  float mrun[4], lrun[4];
  #pragma unroll
  for (int rr = 0; rr < 4; ++rr) { mrun[rr] = -__builtin_inff(); lrun[rr] = 0.f; }

  const int nkt = (kl + 63) >> 6;
  for (int kt = 0; kt < nkt; ++kt) {
    const int k0 = kt * 64;
    uint4 kd[4], vd[4];
    #pragma unroll
    for (int p = 0; p < 4; ++p)
      kd[p] = *(const uint4*)(kg + (size_t)(k0 + p * 16) * 128);
    #pragma unroll
    for (int p = 0; p < 4; ++p)
      vd[p] = *(const uint4*)(vg + (size_t)p * 32 * 1024 + k0);
    __syncthreads();
    #pragma unroll
    for (int p = 0; p < 4; ++p)
      *(uint4*)&Ks[krow + p * 16][kcol * 8] = kd[p];
    #pragma unroll
    for (int p = 0; p < 4; ++p)
      *(uint4*)&Vs[vrow + p * 32][vcol * 8] = vd[p];
    __syncthreads();

    f32x4 s[4];
    #pragma unroll
    for (int ct = 0; ct < 4; ++ct) {
      s[ct] = (f32x4){0.f, 0.f, 0.f, 0.f};
      #pragma unroll
      for (int ks = 0; ks < 4; ++ks) {
        const bf16x8 kf = *(const bf16x8*)&Ks[ct * 16 + lq][ks * 32 + quad * 8];
        s[ct] = MFMA_BF16(qf[ks], kf, s[ct]);
      }
    }
    #pragma unroll
    for (int ct = 0; ct < 4; ++ct) {
      const bool valid = (k0 + ct * 16 + lq) < kl;
      #pragma unroll
      for (int rr = 0; rr < 4; ++rr)
        s[ct][rr] = valid ? s[ct][rr] : -__builtin_inff();
    }
    float mnew[4], alpha[4], rs[4];
    #pragma unroll
    for (int rr = 0; rr < 4; ++rr) {
      float tm = fmaxf(fmaxf(s[0][rr], s[1][rr]), fmaxf(s[2][rr], s[3][rr]));
      tm = fmaxf(tm, __shfl_xor(tm, 1));
      tm = fmaxf(tm, __shfl_xor(tm, 2));
      tm = fmaxf(tm, __shfl_xor(tm, 4));
      tm = fmaxf(tm, __shfl_xor(tm, 8));
      const float mn = fmaxf(mrun[rr], tm);
      alpha[rr] = __expf(mrun[rr] - mn);
      mrun[rr] = mn;
      mnew[rr] = mn;
      rs[rr] = 0.f;
    }
    #pragma unroll
    for (int ct = 0; ct < 4; ++ct)
      #pragma unroll
      for (int rr = 0; rr < 4; ++rr) {
        const float p = __expf(s[ct][rr] - mnew[rr]);
        s[ct][rr] = p;
        rs[rr] += p;
      }
    #pragma unroll
    for (int rr = 0; rr < 4; ++rr) {
      float t = rs[rr];
      t += __shfl_xor(t, 1);
      t += __shfl_xor(t, 2);
      t += __shfl_xor(t, 4);
      t += __shfl_xor(t, 8);
      lrun[rr] = lrun[rr] * alpha[rr] + t;
    }
    #pragma unroll
    for (int j = 0; j < 8; ++j)
      #pragma unroll
      for (int rr = 0; rr < 4; ++rr)
        o[j][rr] *= alpha[rr];

    #pragma unroll
    for (int ct = 0; ct < 4; ++ct)
      #pragma unroll
      for (int rr = 0; rr < 4; ++rr)
        Ps[w * 16 + quad * 4 + rr][ct * 16 + lq] = f2bf(s[ct][rr]);

    bf16x8 pf[2];
    pf[0] = *(const bf16x8*)&Ps[w * 16 + lq][quad * 8];
    pf[1] = *(const bf16x8*)&Ps[w * 16 + lq][32 + quad * 8];

    #pragma unroll
    for (int j = 0; j < 8; ++j) {
      #pragma unroll
      for (int kk = 0; kk < 2; ++kk) {
        const bf16x8 vf = *(const bf16x8*)&Vs[j * 16 + lq][kk * 32 + quad * 8];
        o[j] = MFMA_BF16(pf[kk], vf, o[j]);
      }
    }
  }

  const int h = bh & 15;
  #pragma unroll
  for (int rr = 0; rr < 4; ++rr) {
    const int row = l0 + w * 16 + quad * 4 + rr;
    const float inv = (row < ql) ? (1.0f / lrun[rr]) : 0.0f;
    u16* op = ao + ((size_t)b * 512 + row) * 2048 + h * 128 + lq;
    #pragma unroll
    for (int j = 0; j < 8; ++j)
      op[j * 16] = f2bf(o[j][rr] * inv);
  }
}

extern "C" void kernel_launch(void* const* d_in, const int* in_sizes, int n_in,
                              void* d_out, int out_size, void* d_ws, size_t ws_size,
                              hipStream_t stream) {
  (void)in_sizes; (void)n_in; (void)out_size; (void)ws_size;
  const float* x       = (const float*)d_in[0];
  const float* latents = (const float*)d_in[1];
  const float* t_emb   = (const float*)d_in[2];
  const int*   q_lens  = (const int*)d_in[3];
  const int*   k_lens  = (const int*)d_in[4];
  const float* ln_w    = (const float*)d_in[5];
  const float* ln_b    = (const float*)d_in[6];
  const float* ssg     = (const float*)d_in[7];
  const float* Wq      = (const float*)d_in[8];
  const float* bq      = (const float*)d_in[9];
  const float* Wkv     = (const float*)d_in[10];
  const float* bkv     = (const float*)d_in[11];
  const float* Wo      = (const float*)d_in[12];
  const float* bo      = (const float*)d_in[13];
  float* out = (float*)d_out;

  u16* ws = (u16*)d_ws;
  const size_t MEG = (size_t)1 << 20;      // elements
  u16* WqT  = ws;                 //  4M elems: (2048 x 2048) bf16, N-major
  u16* WoT  = ws + 4  * MEG;      //  4M
  u16* WkvT = ws + 8  * MEG;      //  8M: (4096 x 2048)
  u16* xk   = ws + 16 * MEG;      //  8M: (B*K, 2048)
  u16* lat  = ws + 24 * MEG;      //  4M: (B*L, 2048)
  u16* qb   = ws + 28 * MEG;      //  4M: (B,H,L,C) pre-scaled
  u16* kbuf = ws + 32 * MEG;      //  8M: (B,H,K,C)
  u16* vTb  = ws + 40 * MEG;      //  8M: (B,H,C,K)
  u16* aob  = ws + 48 * MEG;      //  4M: (B*L, 2048)

  prep_kernel<<<dim3(22528), dim3(256), 0, stream>>>(
      x, ln_w, ln_b, latents, t_emb, ssg, Wq, Wo, Wkv,
      xk, lat, WqT, WoT, WkvT);

  // fused q-proj (256 tiles) + kv-proj (1024 tiles)
  gemm_kernel<128, 3><<<dim3(1280), dim3(256), 0, stream>>>(
      lat, WqT, xk, WkvT, bq, bkv, qb, kbuf, vTb, nullptr, nullptr, nullptr);

  attn_kernel<<<dim3(8, 64), dim3(256), 0, stream>>>(qb, kbuf, vTb, k_lens, q_lens, aob);

  gemm_kernel<64, 2><<<dim3(16, 32), dim3(256), 0, stream>>>(
      aob, WoT, nullptr, nullptr, bo, nullptr, nullptr, nullptr, nullptr, out, t_emb, ssg);
}

// Round 7
// 416.719 us; speedup vs baseline: 1.0410x; 1.0410x over previous
//
#include <hip/hip_runtime.h>

typedef unsigned short u16;
typedef short bf16x8 __attribute__((ext_vector_type(8)));
typedef float f32x4 __attribute__((ext_vector_type(4)));

#define MFMA_BF16(a, b, c) __builtin_amdgcn_mfma_f32_16x16x32_bf16((a), (b), (c), 0, 0, 0)
#define ATT_SCALE 0.08838834764831845f  // 1/sqrt(128)

__device__ __forceinline__ u16 f2bf(float f) {
  union { float f; unsigned int u; } cv;
  cv.f = f;
  unsigned int u = cv.u + 0x7fffu + ((cv.u >> 16) & 1u);
  return (u16)(u >> 16);
}

// ---------------- prep: LN(x), AdaLN(latents), W transposes — one dispatch ----------------
__global__ __launch_bounds__(256) void prep_kernel(
    const float* __restrict__ x, const float* __restrict__ ln_w,
    const float* __restrict__ ln_b, const float* __restrict__ latents,
    const float* __restrict__ t_emb, const float* __restrict__ ssg,
    const float* __restrict__ Wq, const float* __restrict__ Wo,
    const float* __restrict__ Wkv,
    u16* __restrict__ xk_out, u16* __restrict__ lat_out,
    u16* __restrict__ WqT, u16* __restrict__ WoT, u16* __restrict__ WkvT)
{
  __shared__ float shmem[32 * 33];
  const int blk = blockIdx.x;
  const int tid = threadIdx.x;
  if (blk < 6144) {
    const bool is_x = blk < 4096;
    const int row = is_x ? blk : blk - 4096;
    const float* src = is_x ? (x + (size_t)row * 2048) : (latents + (size_t)row * 2048);
    const float4* xr = (const float4*)src;
    float4 v0 = xr[tid];
    float4 v1 = xr[tid + 256];
    float sum = v0.x + v0.y + v0.z + v0.w + v1.x + v1.y + v1.z + v1.w;
    float sq  = v0.x*v0.x + v0.y*v0.y + v0.z*v0.z + v0.w*v0.w
              + v1.x*v1.x + v1.y*v1.y + v1.z*v1.z + v1.w*v1.w;
    #pragma unroll
    for (int off = 32; off > 0; off >>= 1) {
      sum += __shfl_xor(sum, off);
      sq  += __shfl_xor(sq, off);
    }
    if ((tid & 63) == 0) { shmem[tid >> 6] = sum; shmem[(tid >> 6) + 4] = sq; }
    __syncthreads();
    sum = shmem[0] + shmem[1] + shmem[2] + shmem[3];
    sq  = shmem[4] + shmem[5] + shmem[6] + shmem[7];
    const float mean = sum * (1.0f / 2048.0f);
    const float var  = sq * (1.0f / 2048.0f) - mean * mean;
    const float rstd = rsqrtf(var + 1e-5f);
    if (is_x) {
      const float4* w4 = (const float4*)ln_w;
      const float4* b4 = (const float4*)ln_b;
      ushort4* orow = (ushort4*)(xk_out + (size_t)row * 2048);
      #pragma unroll
      for (int j = 0; j < 2; ++j) {
        const int idx = tid + j * 256;
        const float4 v = j ? v1 : v0;
        const float4 ww = w4[idx];
        const float4 bb = b4[idx];
        ushort4 o;
        o.x = f2bf((v.x - mean) * rstd * ww.x + bb.x);
        o.y = f2bf((v.y - mean) * rstd * ww.y + bb.y);
        o.z = f2bf((v.z - mean) * rstd * ww.z + bb.z);
        o.w = f2bf((v.w - mean) * rstd * ww.w + bb.w);
        orow[idx] = o;
      }
    } else {
      const int bidx = row >> 9;
      const float4* te = (const float4*)(t_emb + (size_t)bidx * 3 * 2048);
      const float4* sg = (const float4*)ssg;
      ushort4* orow = (ushort4*)(lat_out + (size_t)row * 2048);
      #pragma unroll
      for (int j = 0; j < 2; ++j) {
        const int idx = tid + j * 256;
        const float4 v = j ? v1 : v0;
        const float4 t0 = te[idx];        // shift row
        const float4 t1 = te[512 + idx];  // scale row
        const float4 s0 = sg[idx];
        const float4 s1 = sg[512 + idx];
        ushort4 o;
        o.x = f2bf(((v.x - mean) * rstd) * (1.0f + t1.x + s1.x) + (t0.x + s0.x));
        o.y = f2bf(((v.y - mean) * rstd) * (1.0f + t1.y + s1.y) + (t0.y + s0.y));
        o.z = f2bf(((v.z - mean) * rstd) * (1.0f + t1.z + s1.z) + (t0.z + s0.z));
        o.w = f2bf(((v.w - mean) * rstd) * (1.0f + t1.w + s1.w) + (t0.w + s0.w));
        orow[idx] = o;
      }
    }
  } else {
    int t = blk - 6144;
    const float* in;
    u16* outp;
    int C, cx, ry;
    if (t < 4096)      { in = Wq;  outp = WqT;  C = 2048; cx = t & 63;  ry = t >> 6; }
    else if (t < 8192) { t -= 4096; in = Wo;  outp = WoT;  C = 2048; cx = t & 63;  ry = t >> 6; }
    else               { t -= 8192; in = Wkv; outp = WkvT; C = 4096; cx = t & 127; ry = t >> 7; }
    float (*tile)[33] = (float(*)[33])shmem;
    const int R = 2048;
    const int c0 = cx * 32;
    const int r0 = ry * 32;
    const int tx = tid & 31;
    const int ty = tid >> 5;   // 0..7
    #pragma unroll
    for (int i = 0; i < 4; ++i)
      tile[ty + i * 8][tx] = in[(size_t)(r0 + ty + i * 8) * C + c0 + tx];
    __syncthreads();
    #pragma unroll
    for (int i = 0; i < 4; ++i)
      outp[(size_t)(c0 + ty + i * 8) * R + r0 + tx] = f2bf(tile[tx][ty + i * 8]);
  }
}

// ---------------- bf16 MFMA GEMM: BK=64, register staging pre-barrier (R4 config) ----------------
// mode 0: q proj  -> out_q bf16 (B,H,L,C), fused * ATT_SCALE
// mode 1: kv proj -> out_k bf16 (B,H,K,C), out_vT bf16 (B,H,C,K); tiles fully
//         beyond k_lens[b] skip the K-loop (masked in attention anyway).
// mode 2: out proj-> out_f fp32 (B*L, D), fused * gate
template<int BM>
__global__ __launch_bounds__(256) void gemm_bf16_kernel(
    const u16* __restrict__ A, const u16* __restrict__ BT,
    int Kd, int mode,
    const float* __restrict__ bias,
    u16* __restrict__ out_q, u16* __restrict__ out_k, u16* __restrict__ out_vT,
    float* __restrict__ out_f,
    const float* __restrict__ t_emb, const float* __restrict__ ssg,
    const int* __restrict__ k_lens)
{
  constexpr int TI = BM / 32;        // wave covers BM/2 rows = TI 16-row tiles
  __shared__ u16 As[2][BM][40];      // padded: stride 40 elem = 80B
  __shared__ u16 Bs[2][128][40];
  const int tid  = threadIdx.x;
  const int lane = tid & 63;
  const int wv   = tid >> 6;
  const int wm   = wv & 1, wn = wv >> 1;
  const int quad = lane >> 4, lq = lane & 15;
  const int m0 = blockIdx.y * BM, n0 = blockIdx.x * 128;

  f32x4 acc[TI][4];
  #pragma unroll
  for (int i = 0; i < TI; ++i)
    #pragma unroll
    for (int j = 0; j < 4; ++j)
      acc[i][j] = (f32x4){0.f, 0.f, 0.f, 0.f};

  // masked-key tile skip: whole m-tile beyond k_lens[b] contributes nothing
  int kiters = Kd;
  if (mode == 1 && (m0 & 1023) >= k_lens[m0 >> 10]) kiters = 0;

  const int rB  = tid >> 1;
  const int hfB = (tid & 1) * 16;
  const u16* gB = BT + (size_t)(n0 + rB) * Kd + hfB;
  const int rA  = (BM == 128) ? (tid >> 1) : (tid >> 2);
  const int hA  = (BM == 128) ? 0 : ((tid >> 1) & 1);
  const int hfA = (tid & 1) * 16;
  const u16* gA = A + (size_t)(m0 + rA) * Kd + hA * 32 + hfA;

  for (int k0 = 0; k0 < kiters; k0 += 64) {
    // loads in flight BEFORE the barrier: latency overlaps barrier wait +
    // other waves' MFMAs (register loads need no vmcnt drain at s_barrier).
    uint4 a00, a01, a10, a11;
    a00 = *(const uint4*)(gA + k0);
    a01 = *(const uint4*)(gA + k0 + 8);
    if (BM == 128) {
      a10 = *(const uint4*)(gA + k0 + 32);
      a11 = *(const uint4*)(gA + k0 + 40);
    }
    const uint4 b00 = *(const uint4*)(gB + k0);
    const uint4 b01 = *(const uint4*)(gB + k0 + 8);
    const uint4 b10 = *(const uint4*)(gB + k0 + 32);
    const uint4 b11 = *(const uint4*)(gB + k0 + 40);
    __syncthreads();                 // prior iteration's LDS reads done
    *(uint4*)&As[hA][rA][hfA]     = a00;
    *(uint4*)&As[hA][rA][hfA + 8] = a01;
    if (BM == 128) {
      *(uint4*)&As[1][rA][hfA]     = a10;
      *(uint4*)&As[1][rA][hfA + 8] = a11;
    }
    *(uint4*)&Bs[0][rB][hfB]     = b00;
    *(uint4*)&Bs[0][rB][hfB + 8] = b01;
    *(uint4*)&Bs[1][rB][hfB]     = b10;
    *(uint4*)&Bs[1][rB][hfB + 8] = b11;
    __syncthreads();
    #pragma unroll
    for (int kk = 0; kk < 2; ++kk) {
      bf16x8 av[TI], bv[4];
      #pragma unroll
      for (int i = 0; i < TI; ++i)
        av[i] = *(const bf16x8*)&As[kk][wm * (BM / 2) + i * 16 + lq][quad * 8];
      #pragma unroll
      for (int j = 0; j < 4; ++j)
        bv[j] = *(const bf16x8*)&Bs[kk][wn * 64 + j * 16 + lq][quad * 8];
      #pragma unroll
      for (int i = 0; i < TI; ++i)
        #pragma unroll
        for (int j = 0; j < 4; ++j)
          acc[i][j] = MFMA_BF16(av[i], bv[j], acc[i][j]);
    }
  }

  // epilogue; C/D layout: col = lane&15, row = quad*4 + reg
  #pragma unroll
  for (int i = 0; i < TI; ++i) {
    const int mlb = m0 + wm * (BM / 2) + i * 16 + quad * 4;
    #pragma unroll
    for (int j = 0; j < 4; ++j) {
      const int n = n0 + wn * 64 + j * 16 + lq;
      const float bs = bias[n];
      if (mode == 0) {
        const int h = n >> 7, c = n & 127;
        #pragma unroll
        for (int rr = 0; rr < 4; ++rr) {
          const int m = mlb + rr;
          const int bb = m >> 9, l = m & 511;
          out_q[((size_t)(bb * 16 + h) * 512 + l) * 128 + c] =
              f2bf((acc[i][j][rr] + bs) * ATT_SCALE);
        }
      } else if (mode == 1) {
        if (n < 2048) {
          const int h = n >> 7, c = n & 127;
          #pragma unroll
          for (int rr = 0; rr < 4; ++rr) {
            const int m = mlb + rr;
            const int bb = m >> 10, kk = m & 1023;
            out_k[((size_t)(bb * 16 + h) * 1024 + kk) * 128 + c] = f2bf(acc[i][j][rr] + bs);
          }
        } else {
          const int n2 = n - 2048;
          const int h = n2 >> 7, c = n2 & 127;
          #pragma unroll
          for (int rr = 0; rr < 4; ++rr) {
            const int m = mlb + rr;
            const int bb = m >> 10, kk = m & 1023;
            out_vT[((size_t)(bb * 16 + h) * 128 + c) * 1024 + kk] = f2bf(acc[i][j][rr] + bs);
          }
        }
      } else {
        #pragma unroll
        for (int rr = 0; rr < 4; ++rr) {
          const int m = mlb + rr;
          const int bb = m >> 9;
          const float g = t_emb[((size_t)bb * 3 + 2) * 2048 + n] + ssg[2 * 2048 + n];
          out_f[(size_t)m * 2048 + n] = (acc[i][j][rr] + bs) * g;
        }
      }
    }
  }
}

// ---------------- flash attention: LDS-staged K/V, pre-barrier staging ----------------
// per (b,h, 64-row q tile); Q pre-scaled by 1/sqrt(C) in q-proj epilogue.
__global__ __launch_bounds__(256) void attn_kernel(
    const u16* __restrict__ qb, const u16* __restrict__ kb,
    const u16* __restrict__ vT, const int* __restrict__ k_lens,
    const int* __restrict__ q_lens, u16* __restrict__ ao)
{
  __shared__ u16 Ks[64][132];   // keys x C; stride 264B -> 2-way banks (free)
  __shared__ u16 Vs[128][68];   // c x keys; stride 136B
  __shared__ u16 Ps[64][68];    // q x keys (wave-private 16-row bands)
  const int tid  = threadIdx.x;
  const int w    = tid >> 6;
  const int lane = tid & 63;
  const int quad = lane >> 4, lq = lane & 15;
  const int bh = blockIdx.y;           // b*16 + h
  const int b  = bh >> 4;
  const int l0 = blockIdx.x * 64;
  const int kl = k_lens[b];
  const int ql = q_lens[b];

  bf16x8 qf[4];
  {
    const u16* qp = qb + ((size_t)bh * 512 + l0 + w * 16 + lq) * 128 + quad * 8;
    #pragma unroll
    for (int ks = 0; ks < 4; ++ks)
      qf[ks] = *(const bf16x8*)(qp + ks * 32);
  }

  const int krow = tid >> 4;
  const int kcol = tid & 15;
  const u16* kg = kb + ((size_t)bh * 1024 + krow) * 128 + kcol * 8;
  const int vrow = tid >> 3;
  const int vcol = tid & 7;
  const u16* vg = vT + (size_t)bh * 128 * 1024 + (size_t)vrow * 1024 + vcol * 8;

  f32x4 o[8];
  #pragma unroll
  for (int j = 0; j < 8; ++j) o[j] = (f32x4){0.f, 0.f, 0.f, 0.f};
  float mrun[4], lrun[4];
  #pragma unroll
  for (int rr = 0; rr < 4; ++rr) { mrun[rr] = -__builtin_inff(); lrun[rr] = 0.f; }

  const int nkt = (kl + 63) >> 6;
  for (int kt = 0; kt < nkt; ++kt) {
    const int k0 = kt * 64;
    uint4 kd[4], vd[4];
    #pragma unroll
    for (int p = 0; p < 4; ++p)
      kd[p] = *(const uint4*)(kg + (size_t)(k0 + p * 16) * 128);
    #pragma unroll
    for (int p = 0; p < 4; ++p)
      vd[p] = *(const uint4*)(vg + (size_t)p * 32 * 1024 + k0);
    __syncthreads();
    #pragma unroll
    for (int p = 0; p < 4; ++p)
      *(uint4*)&Ks[krow + p * 16][kcol * 8] = kd[p];
    #pragma unroll
    for (int p = 0; p < 4; ++p)
      *(uint4*)&Vs[vrow + p * 32][vcol * 8] = vd[p];
    __syncthreads();

    f32x4 s[4];
    #pragma unroll
    for (int ct = 0; ct < 4; ++ct) {
      s[ct] = (f32x4){0.f, 0.f, 0.f, 0.f};
      #pragma unroll
      for (int ks = 0; ks < 4; ++ks) {
        const bf16x8 kf = *(const bf16x8*)&Ks[ct * 16 + lq][ks * 32 + quad * 8];
        s[ct] = MFMA_BF16(qf[ks], kf, s[ct]);
      }
    }
    #pragma unroll
    for (int ct = 0; ct < 4; ++ct) {
      const bool valid = (k0 + ct * 16 + lq) < kl;
      #pragma unroll
      for (int rr = 0; rr < 4; ++rr)
        s[ct][rr] = valid ? s[ct][rr] : -__builtin_inff();
    }
    float mnew[4], alpha[4], rs[4];
    #pragma unroll
    for (int rr = 0; rr < 4; ++rr) {
      float tm = fmaxf(fmaxf(s[0][rr], s[1][rr]), fmaxf(s[2][rr], s[3][rr]));
      tm = fmaxf(tm, __shfl_xor(tm, 1));
      tm = fmaxf(tm, __shfl_xor(tm, 2));
      tm = fmaxf(tm, __shfl_xor(tm, 4));
      tm = fmaxf(tm, __shfl_xor(tm, 8));
      const float mn = fmaxf(mrun[rr], tm);
      alpha[rr] = __expf(mrun[rr] - mn);
      mrun[rr] = mn;
      mnew[rr] = mn;
      rs[rr] = 0.f;
    }
    #pragma unroll
    for (int ct = 0; ct < 4; ++ct)
      #pragma unroll
      for (int rr = 0; rr < 4; ++rr) {
        const float p = __expf(s[ct][rr] - mnew[rr]);
        s[ct][rr] = p;
        rs[rr] += p;
      }
    #pragma unroll
    for (int rr = 0; rr < 4; ++rr) {
      float t = rs[rr];
      t += __shfl_xor(t, 1);
      t += __shfl_xor(t, 2);
      t += __shfl_xor(t, 4);
      t += __shfl_xor(t, 8);
      lrun[rr] = lrun[rr] * alpha[rr] + t;
    }
    #pragma unroll
    for (int j = 0; j < 8; ++j)
      #pragma unroll
      for (int rr = 0; rr < 4; ++rr)
        o[j][rr] *= alpha[rr];

    #pragma unroll
    for (int ct = 0; ct < 4; ++ct)
      #pragma unroll
      for (int rr = 0; rr < 4; ++rr)
        Ps[w * 16 + quad * 4 + rr][ct * 16 + lq] = f2bf(s[ct][rr]);

    bf16x8 pf[2];
    pf[0] = *(const bf16x8*)&Ps[w * 16 + lq][quad * 8];
    pf[1] = *(const bf16x8*)&Ps[w * 16 + lq][32 + quad * 8];

    #pragma unroll
    for (int j = 0; j < 8; ++j) {
      #pragma unroll
      for (int kk = 0; kk < 2; ++kk) {
        const bf16x8 vf = *(const bf16x8*)&Vs[j * 16 + lq][kk * 32 + quad * 8];
        o[j] = MFMA_BF16(pf[kk], vf, o[j]);
      }
    }
  }

  const int h = bh & 15;
  #pragma unroll
  for (int rr = 0; rr < 4; ++rr) {
    const int row = l0 + w * 16 + quad * 4 + rr;
    const float inv = (row < ql) ? (1.0f / lrun[rr]) : 0.0f;
    u16* op = ao + ((size_t)b * 512 + row) * 2048 + h * 128 + lq;
    #pragma unroll
    for (int j = 0; j < 8; ++j)
      op[j * 16] = f2bf(o[j][rr] * inv);
  }
}

extern "C" void kernel_launch(void* const* d_in, const int* in_sizes, int n_in,
                              void* d_out, int out_size, void* d_ws, size_t ws_size,
                              hipStream_t stream) {
  (void)in_sizes; (void)n_in; (void)out_size; (void)ws_size;
  const float* x       = (const float*)d_in[0];
  const float* latents = (const float*)d_in[1];
  const float* t_emb   = (const float*)d_in[2];
  const int*   q_lens  = (const int*)d_in[3];
  const int*   k_lens  = (const int*)d_in[4];
  const float* ln_w    = (const float*)d_in[5];
  const float* ln_b    = (const float*)d_in[6];
  const float* ssg     = (const float*)d_in[7];
  const float* Wq      = (const float*)d_in[8];
  const float* bq      = (const float*)d_in[9];
  const float* Wkv     = (const float*)d_in[10];
  const float* bkv     = (const float*)d_in[11];
  const float* Wo      = (const float*)d_in[12];
  const float* bo      = (const float*)d_in[13];
  float* out = (float*)d_out;

  u16* ws = (u16*)d_ws;
  const size_t MEG = (size_t)1 << 20;      // elements
  u16* WqT  = ws;                 //  4M elems: (2048 x 2048) bf16, N-major
  u16* WoT  = ws + 4  * MEG;      //  4M
  u16* WkvT = ws + 8  * MEG;      //  8M: (4096 x 2048)
  u16* xk   = ws + 16 * MEG;      //  8M: (B*K, 2048)
  u16* lat  = ws + 24 * MEG;      //  4M: (B*L, 2048)
  u16* qb   = ws + 28 * MEG;      //  4M: (B,H,L,C) pre-scaled
  u16* kbuf = ws + 32 * MEG;      //  8M: (B,H,K,C)
  u16* vTb  = ws + 40 * MEG;      //  8M: (B,H,C,K)
  u16* aob  = ws + 48 * MEG;      //  4M: (B*L, 2048)

  prep_kernel<<<dim3(22528), dim3(256), 0, stream>>>(
      x, ln_w, ln_b, latents, t_emb, ssg, Wq, Wo, Wkv,
      xk, lat, WqT, WoT, WkvT);

  // q = lat @ Wq + bq  (fused *1/sqrt(C))
  gemm_bf16_kernel<64><<<dim3(16, 32), dim3(256), 0, stream>>>(
      lat, WqT, 2048, 0, bq, qb, nullptr, nullptr, nullptr, nullptr, nullptr, k_lens);
  // kv = xk @ Wkv + bkv  (tiles beyond k_lens skip K-loop)
  gemm_bf16_kernel<128><<<dim3(32, 32), dim3(256), 0, stream>>>(
      xk, WkvT, 2048, 1, bkv, nullptr, kbuf, vTb, nullptr, nullptr, nullptr, k_lens);

  attn_kernel<<<dim3(8, 64), dim3(256), 0, stream>>>(qb, kbuf, vTb, k_lens, q_lens, aob);

  // out = (attn_out @ Wo + bo) * gate
  gemm_bf16_kernel<64><<<dim3(16, 32), dim3(256), 0, stream>>>(
      aob, WoT, 2048, 2, bo, nullptr, nullptr, nullptr, out, t_emb, ssg, k_lens);
}